// Round 1
// baseline (1772.279 us; speedup 1.0000x reference)
//
#include <hip/hip_runtime.h>
#include <hip/hip_bf16.h>

// Problem constants (fixed by the reference):
//   x: [4,2048,4096] fp32 -> M=8192 tokens, K=4096
//   ternary_weight: [16384,4096] int32 in {-1,0,1} -> N=16384
//   out: [8192,16384] fp32
#define M_TOK 8192
#define N_OUT 16384
#define K_IN  4096

typedef int v4i __attribute__((ext_vector_type(4)));

// ---------------------------------------------------------------------------
// Kernel 1: weight int32 -> int8 pack. 4 elements per thread.
// ---------------------------------------------------------------------------
__global__ __launch_bounds__(256) void cvt_w_kernel(const int* __restrict__ w,
                                                    signed char* __restrict__ w8) {
    size_t i = (size_t)blockIdx.x * blockDim.x + threadIdx.x;  // over 16777216
    int4 v = ((const int4*)w)[i];
    char4 q;
    q.x = (signed char)v.x;
    q.y = (signed char)v.y;
    q.z = (signed char)v.z;
    q.w = (signed char)v.w;
    ((char4*)w8)[i] = q;
}

// ---------------------------------------------------------------------------
// Kernel 2: per-token dynamic int8 quantization.
// One block (256 threads) per token row of 4096 floats.
// act_scale = max(max|x|, 1e-5) / 127 ; q = clip(rint(x/act_scale), -128, 127)
// rintf == round-half-even == np.round; IEEE fp32 division matches numpy.
// ---------------------------------------------------------------------------
__global__ __launch_bounds__(256) void quant_kernel(const float* __restrict__ x,
                                                    signed char* __restrict__ qx,
                                                    float* __restrict__ scales) {
    int token = blockIdx.x;
    const float4* xr = (const float4*)(x + (size_t)token * K_IN);
    int t = threadIdx.x;

    float4 v[4];
    float m = 0.f;
#pragma unroll
    for (int u = 0; u < 4; ++u) {
        v[u] = xr[u * 256 + t];
        m = fmaxf(m, fmaxf(fmaxf(fabsf(v[u].x), fabsf(v[u].y)),
                           fmaxf(fabsf(v[u].z), fabsf(v[u].w))));
    }
    // wave (64-lane) max reduce
#pragma unroll
    for (int off = 32; off > 0; off >>= 1) m = fmaxf(m, __shfl_xor(m, off));

    __shared__ float wmax[4];
    int lane = t & 63, w = t >> 6;
    if (lane == 0) wmax[w] = m;
    __syncthreads();
    float bm = fmaxf(fmaxf(wmax[0], wmax[1]), fmaxf(wmax[2], wmax[3]));
    float scale = fmaxf(bm, 1e-5f) / 127.0f;
    if (t == 0) scales[token] = scale;

    char4* qr = (char4*)(qx + (size_t)token * K_IN);
#pragma unroll
    for (int u = 0; u < 4; ++u) {
        float4 f = v[u];
        char4 q;
        q.x = (signed char)(int)fminf(fmaxf(rintf(f.x / scale), -128.f), 127.f);
        q.y = (signed char)(int)fminf(fmaxf(rintf(f.y / scale), -128.f), 127.f);
        q.z = (signed char)(int)fminf(fmaxf(rintf(f.z / scale), -128.f), 127.f);
        q.w = (signed char)(int)fminf(fmaxf(rintf(f.w / scale), -128.f), 127.f);
        qr[u * 256 + t] = q;
    }
}

// ---------------------------------------------------------------------------
// Kernel 3: int8 GEMM  out[m,n] = i32dot(qx[m,:], w8[n,:]) * scales[m]*wsc + bias[n]
// 128x128 tile, BK=64, 256 threads = 4 waves in 2x2, each wave 64x64 via
// 4x4 grid of mfma_i32_16x16x64_i8.
// LDS layout: [kchunk(4)][row(128)][16B] so both the global_load_lds staging
// (wave-uniform base + lane*16) and the ds_read_b128 fragment reads
// (16 lanes -> 256 contiguous bytes, 2-way bank alias = free) work.
// A-fragment: row = lane&15 (+16i), k = (lane>>4)*16 + j  (16 contiguous bytes)
// B-fragment: col = lane&15 (+16j), same k split.
// C/D: col = lane&15, row = (lane>>4)*4 + reg   [m89, dtype-independent]
// ---------------------------------------------------------------------------
#define TM 128
#define TN 128
#define TK 64

__global__ __launch_bounds__(256) void gemm_kernel(
    const signed char* __restrict__ A,   // [M_TOK][K_IN] qx
    const signed char* __restrict__ B,   // [N_OUT][K_IN] w8
    const float* __restrict__ scales,    // [M_TOK]
    const float* __restrict__ wscale,    // [1]
    const float* __restrict__ bias,      // [N_OUT]
    float* __restrict__ out)             // [M_TOK][N_OUT]
{
    __shared__ __align__(16) signed char smA[4][TM][16];  // 8 KB
    __shared__ __align__(16) signed char smB[4][TN][16];  // 8 KB

    const int t = threadIdx.x;
    const int lane = t & 63;
    const int w = t >> 6;
    const int wm = w >> 1;   // 0..1
    const int wn = w & 1;    // 0..1
    const int m0 = blockIdx.y * TM;
    const int n0 = blockIdx.x * TN;

    // Staging: chunk s (0..511) -> LDS bytes [s*16, s*16+16), global (row=s&127, kc=s>>7)
    // s_lo = t, s_hi = t + 256.
    const signed char* ga_lo = A + (size_t)(m0 + (t & 127)) * K_IN + (t >> 7) * 16;
    const signed char* ga_hi = ga_lo + 32;  // kc += 2
    const signed char* gb_lo = B + (size_t)(n0 + (t & 127)) * K_IN + (t >> 7) * 16;
    const signed char* gb_hi = gb_lo + 32;

    // wave-uniform LDS bases (HW adds lane*16)
    signed char* lA_lo = &smA[0][0][0] + w * 1024;
    signed char* lA_hi = &smA[0][0][0] + 4096 + w * 1024;
    signed char* lB_lo = &smB[0][0][0] + w * 1024;
    signed char* lB_hi = &smB[0][0][0] + 4096 + w * 1024;

    v4i acc[4][4] = {};

    const int r = lane & 15;
    const int g = lane >> 4;

    for (int k0 = 0; k0 < K_IN; k0 += TK) {
        __syncthreads();  // previous compute done before overwriting LDS
        __builtin_amdgcn_global_load_lds(
            (const __attribute__((address_space(1))) void*)(ga_lo + k0),
            (__attribute__((address_space(3))) void*)lA_lo, 16, 0, 0);
        __builtin_amdgcn_global_load_lds(
            (const __attribute__((address_space(1))) void*)(ga_hi + k0),
            (__attribute__((address_space(3))) void*)lA_hi, 16, 0, 0);
        __builtin_amdgcn_global_load_lds(
            (const __attribute__((address_space(1))) void*)(gb_lo + k0),
            (__attribute__((address_space(3))) void*)lB_lo, 16, 0, 0);
        __builtin_amdgcn_global_load_lds(
            (const __attribute__((address_space(1))) void*)(gb_hi + k0),
            (__attribute__((address_space(3))) void*)lB_hi, 16, 0, 0);
        __syncthreads();  // drains vmcnt -> tiles resident in LDS

        v4i a[4], b[4];
#pragma unroll
        for (int i = 0; i < 4; ++i)
            a[i] = *(const v4i*)&smA[g][wm * 64 + i * 16 + r][0];
#pragma unroll
        for (int j = 0; j < 4; ++j)
            b[j] = *(const v4i*)&smB[g][wn * 64 + j * 16 + r][0];

#pragma unroll
        for (int i = 0; i < 4; ++i)
#pragma unroll
            for (int j = 0; j < 4; ++j)
                acc[i][j] = __builtin_amdgcn_mfma_i32_16x16x64_i8(a[i], b[j], acc[i][j], 0, 0, 0);
    }

    // Epilogue: out = acc * scales[m]*wsc + bias[n]
    const float wsc = wscale[0];
    const int col0 = n0 + wn * 64 + (lane & 15);
    const int rbase = (lane >> 4) * 4;
#pragma unroll
    for (int i = 0; i < 4; ++i) {
        const int rowA = m0 + wm * 64 + i * 16 + rbase;
#pragma unroll
        for (int rr = 0; rr < 4; ++rr) {
            const float as_ = scales[rowA + rr] * wsc;
            float* orow = out + (size_t)(rowA + rr) * N_OUT;
#pragma unroll
            for (int j = 0; j < 4; ++j) {
                const int c = col0 + j * 16;
                orow[c] = (float)acc[i][j][rr] * as_ + bias[c];
            }
        }
    }
}

// ---------------------------------------------------------------------------
extern "C" void kernel_launch(void* const* d_in, const int* in_sizes, int n_in,
                              void* d_out, int out_size, void* d_ws, size_t ws_size,
                              hipStream_t stream) {
    const float* x      = (const float*)d_in[0];   // [8192*4096] fp32
    const int*   tw     = (const int*)d_in[1];     // [16384*4096] int32
    const float* wscale = (const float*)d_in[2];   // [1]
    const float* bias   = (const float*)d_in[3];   // [16384]
    float* out = (float*)d_out;                    // [8192*16384] fp32

    // workspace layout: qx (32MB) | w8 (64MB) | scales (32KB)
    signed char* qx = (signed char*)d_ws;
    signed char* w8 = qx + (size_t)M_TOK * K_IN;
    float* scales = (float*)(w8 + (size_t)N_OUT * K_IN);

    // 1) weight pack: 16384*4096/4 = 16777216 char4 -> 65536 blocks
    cvt_w_kernel<<<65536, 256, 0, stream>>>(tw, w8);
    // 2) per-token quantization: one block per token
    quant_kernel<<<M_TOK, 256, 0, stream>>>(x, qx, scales);
    // 3) int8 GEMM: grid (N/128, M/128) = (128, 64)
    dim3 grid(N_OUT / TN, M_TOK / TM);
    gemm_kernel<<<grid, 256, 0, stream>>>(qx, w8, scales, wscale, bias, out);
}